// Round 4
// baseline (482.919 us; speedup 1.0000x reference)
//
#include <hip/hip_runtime.h>
#include <hip/hip_bf16.h>

#define NN 50000
#define NE 600000
#define NG 512

typedef __attribute__((ext_vector_type(8))) short bf16x8;
typedef __attribute__((ext_vector_type(4))) float f32x4;

__device__ __forceinline__ float bf_lo(unsigned u) {
    unsigned v = u << 16;
    return __builtin_bit_cast(float, v);
}
__device__ __forceinline__ float bf_hi(unsigned u) {
    unsigned v = u & 0xFFFF0000u;
    return __builtin_bit_cast(float, v);
}
__device__ __forceinline__ unsigned f2bf(float f) {  // RNE, returns in low 16 bits
    unsigned u = __builtin_bit_cast(unsigned, f);
    return (u + 0x7FFFu + ((u >> 16) & 1u)) >> 16;
}

__global__ __launch_bounds__(256) void k_zero(float* p, int n) {
    int i = blockIdx.x * 256 + threadIdx.x;
    if (i < n) p[i] = 0.0f;
}

__global__ __launch_bounds__(256) void k_hist(const int* __restrict__ dst, int* __restrict__ deg) {
    int e = blockIdx.x * 256 + threadIdx.x;
    if (e < NE) atomicAdd(&deg[dst[e]], 1);
}

__global__ __launch_bounds__(256) void k_counts(const int* __restrict__ batch, float* __restrict__ counts) {
    int i = blockIdx.x * 256 + threadIdx.x;
    if (i < NN) atomicAdd(&counts[batch[i]], 1.0f);
}

__global__ __launch_bounds__(256) void k_alloc(const int* __restrict__ deg, int* __restrict__ gcur,
                                               int* __restrict__ rowstart, int* __restrict__ cursor,
                                               float* __restrict__ dis) {
    int i = blockIdx.x * 256 + threadIdx.x;
    if (i >= NN) return;
    int d = deg[i];
    int st = atomicAdd(gcur, d);
    rowstart[i] = st;
    cursor[i] = st;
    dis[i] = 1.0f / sqrtf((float)(d + 1));
}

__global__ __launch_bounds__(256) void k_fill(const int* __restrict__ src, const int* __restrict__ dst,
                                              const float* __restrict__ dis, int* __restrict__ cursor,
                                              int* __restrict__ csrc, float* __restrict__ cw) {
    int e = blockIdx.x * 256 + threadIdx.x;
    if (e >= NE) return;
    int s = src[e], d = dst[e];
    int slot = atomicAdd(&cursor[d], 1);
    csrc[slot] = s;
    cw[slot] = dis[s] * dis[d];
}

// x (f32) -> bf16 packed
__global__ __launch_bounds__(256) void k_cvt_x(const float4* __restrict__ in, uint2* __restrict__ out, int n4) {
    int i = blockIdx.x * 256 + threadIdx.x;
    if (i >= n4) return;
    float4 v = in[i];
    uint2 o;
    o.x = f2bf(v.x) | (f2bf(v.y) << 16);
    o.y = f2bf(v.z) | (f2bf(v.w) << 16);
    out[i] = o;
}

// W[k][c] f32 -> Wt[c][k] bf16, for 3 weight matrices
__global__ __launch_bounds__(256) void k_cvt_w(const float* __restrict__ W0, const float* __restrict__ W1,
                                               const float* __restrict__ W2, unsigned short* __restrict__ Wt) {
    int idx = blockIdx.x * 256 + threadIdx.x;
    if (idx >= 3 * 16384) return;
    int m = idx >> 14;
    int r = idx & 16383;
    int k = r >> 7, c = r & 127;
    const float* W = (m == 0) ? W0 : (m == 1) ? W1 : W2;
    Wt[m * 16384 + c * 128 + k] = (unsigned short)f2bf(W[k * 128 + c]);
}

// C[M,128](bf16) = A[M,128](bf16) @ W[128,128], W given transposed Wt[col][k] bf16.
// 256 thr = 4 waves; each wave: 16 rows x 128 cols via mfma_f32_16x16x32_bf16.
__global__ __launch_bounds__(256) void k_gemm_mfma(const unsigned short* __restrict__ A,
                                                   const unsigned short* __restrict__ Wt,
                                                   unsigned short* __restrict__ C, int M) {
    int wave = threadIdx.x >> 6;
    int lane = threadIdx.x & 63;
    int rowbase = blockIdx.x * 64 + wave * 16;
    int lr = lane & 15;   // A row within tile / B col within tile
    int kg = lane >> 4;   // k-group 0..3 (8 elems each)

    int arow = rowbase + lr;
    if (arow >= M) arow = M - 1;
    bf16x8 a[4];
#pragma unroll
    for (int kt = 0; kt < 4; ++kt)
        a[kt] = *(const bf16x8*)&A[arow * 128 + kt * 32 + kg * 8];

    f32x4 acc[8];
#pragma unroll
    for (int nt = 0; nt < 8; ++nt) acc[nt] = (f32x4){0.f, 0.f, 0.f, 0.f};

#pragma unroll
    for (int nt = 0; nt < 8; ++nt) {
        const unsigned short* wp = &Wt[(nt * 16 + lr) * 128 + kg * 8];
#pragma unroll
        for (int kt = 0; kt < 4; ++kt) {
            bf16x8 b = *(const bf16x8*)&wp[kt * 32];
            acc[nt] = __builtin_amdgcn_mfma_f32_16x16x32_bf16(a[kt], b, acc[nt], 0, 0, 0);
        }
    }

    int crow0 = rowbase + (lane >> 4) * 4;  // C/D: col = lane&15, row = (lane>>4)*4 + r
#pragma unroll
    for (int nt = 0; nt < 8; ++nt) {
#pragma unroll
        for (int r = 0; r < 4; ++r) {
            int gr = crow0 + r;
            if (gr < M) C[gr * 128 + nt * 16 + lr] = (unsigned short)f2bf(acc[nt][r]);
        }
    }
}

// Gather aggregation, ONE NODE PER WAVE. 4 lane-groups of 16 process 4 edges
// concurrently (uint4 = 8 bf16 per lane), unrolled x2 -> 8 row-gathers in
// flight per wave. Butterfly-reduce groups, fuse self-loop + bias + relu.
template <int POOL>
__global__ __launch_bounds__(256) void k_gather(const uint4* __restrict__ h,
                                                const int* __restrict__ rowstart,
                                                const int* __restrict__ rowend,
                                                const int* __restrict__ csrc,
                                                const float* __restrict__ cw,
                                                const float* __restrict__ dis,
                                                const float* __restrict__ bias,
                                                uint4* __restrict__ outbuf,
                                                const int* __restrict__ batch,
                                                float* __restrict__ sums) {
    int node = (blockIdx.x * 256 + threadIdx.x) >> 6;
    if (node >= NN) return;
    int lane = threadIdx.x & 63;
    int g = lane >> 4;    // edge group 0..3
    int sl = lane & 15;   // feature slot: 8 bf16 = 16 B

    int s0 = rowstart[node];
    int e0 = rowend[node];

    float a[8];
#pragma unroll
    for (int j = 0; j < 8; ++j) a[j] = 0.f;

    for (int i = s0; i < e0; i += 8) {
        int ia = i + g;
        int ib = i + 4 + g;
        bool oka = ia < e0;
        bool okb = ib < e0;
        int sa = oka ? ia : s0;
        int sb = okb ? ib : s0;
        int sna = csrc[sa];
        int snb = csrc[sb];
        float wa = oka ? cw[sa] : 0.f;
        float wb = okb ? cw[sb] : 0.f;
        uint4 va = h[sna * 16 + sl];
        uint4 vb = h[snb * 16 + sl];
        a[0] = fmaf(bf_lo(va.x), wa, a[0]);
        a[1] = fmaf(bf_hi(va.x), wa, a[1]);
        a[2] = fmaf(bf_lo(va.y), wa, a[2]);
        a[3] = fmaf(bf_hi(va.y), wa, a[3]);
        a[4] = fmaf(bf_lo(va.z), wa, a[4]);
        a[5] = fmaf(bf_hi(va.z), wa, a[5]);
        a[6] = fmaf(bf_lo(va.w), wa, a[6]);
        a[7] = fmaf(bf_hi(va.w), wa, a[7]);
        a[0] = fmaf(bf_lo(vb.x), wb, a[0]);
        a[1] = fmaf(bf_hi(vb.x), wb, a[1]);
        a[2] = fmaf(bf_lo(vb.y), wb, a[2]);
        a[3] = fmaf(bf_hi(vb.y), wb, a[3]);
        a[4] = fmaf(bf_lo(vb.z), wb, a[4]);
        a[5] = fmaf(bf_hi(vb.z), wb, a[5]);
        a[6] = fmaf(bf_lo(vb.w), wb, a[6]);
        a[7] = fmaf(bf_hi(vb.w), wb, a[7]);
    }

    // fold the 4 edge-groups
#pragma unroll
    for (int j = 0; j < 8; ++j) {
        a[j] += __shfl_xor(a[j], 16);
        a[j] += __shfl_xor(a[j], 32);
    }

    // self-loop + bias + relu (uniform across groups)
    float d = dis[node];
    float w0 = d * d;
    uint4 hv = h[node * 16 + sl];
    a[0] = fmaf(bf_lo(hv.x), w0, a[0]);
    a[1] = fmaf(bf_hi(hv.x), w0, a[1]);
    a[2] = fmaf(bf_lo(hv.y), w0, a[2]);
    a[3] = fmaf(bf_hi(hv.y), w0, a[3]);
    a[4] = fmaf(bf_lo(hv.z), w0, a[4]);
    a[5] = fmaf(bf_hi(hv.z), w0, a[5]);
    a[6] = fmaf(bf_lo(hv.w), w0, a[6]);
    a[7] = fmaf(bf_hi(hv.w), w0, a[7]);
    float4 ba = ((const float4*)bias)[sl * 2];
    float4 bb = ((const float4*)bias)[sl * 2 + 1];
    a[0] = fmaxf(a[0] + ba.x, 0.f);
    a[1] = fmaxf(a[1] + ba.y, 0.f);
    a[2] = fmaxf(a[2] + ba.z, 0.f);
    a[3] = fmaxf(a[3] + ba.w, 0.f);
    a[4] = fmaxf(a[4] + bb.x, 0.f);
    a[5] = fmaxf(a[5] + bb.y, 0.f);
    a[6] = fmaxf(a[6] + bb.z, 0.f);
    a[7] = fmaxf(a[7] + bb.w, 0.f);

    if (g == 0) {
        if (POOL == 0) {
            uint4 o;
            o.x = f2bf(a[0]) | (f2bf(a[1]) << 16);
            o.y = f2bf(a[2]) | (f2bf(a[3]) << 16);
            o.z = f2bf(a[4]) | (f2bf(a[5]) << 16);
            o.w = f2bf(a[6]) | (f2bf(a[7]) << 16);
            outbuf[node * 16 + sl] = o;
        } else {
            int gg = batch[node];
            float* o = sums + gg * 128 + sl * 8;
#pragma unroll
            for (int j = 0; j < 8; ++j) atomicAdd(o + j, a[j]);
        }
    }
}

// 512 blocks x 64 threads: pooled = sums/count; logits = pooled@Wf + bf; log_softmax
__global__ __launch_bounds__(64) void k_head(const float* __restrict__ sums,
                                             const float* __restrict__ counts,
                                             const float* __restrict__ Wf,
                                             const float* __restrict__ bf,
                                             float* __restrict__ out) {
    int g = blockIdx.x;
    int l = threadIdx.x;
    float inv = 1.0f / fmaxf(counts[g], 1.0f);
    float p0 = sums[g * 128 + l] * inv;
    float p1 = sums[g * 128 + 64 + l] * inv;
    float logit[10];
#pragma unroll
    for (int o = 0; o < 10; ++o) {
        float part = p0 * Wf[l * 10 + o] + p1 * Wf[(l + 64) * 10 + o];
#pragma unroll
        for (int s = 32; s > 0; s >>= 1) part += __shfl_xor(part, s);
        logit[o] = part + bf[o];
    }
    if (l == 0) {
        float m = logit[0];
#pragma unroll
        for (int o = 1; o < 10; ++o) m = fmaxf(m, logit[o]);
        float sum = 0.f;
#pragma unroll
        for (int o = 0; o < 10; ++o) sum += expf(logit[o] - m);
        float lse = m + logf(sum);
#pragma unroll
        for (int o = 0; o < 10; ++o) out[g * 10 + o] = logit[o] - lse;
    }
}

extern "C" void kernel_launch(void* const* d_in, const int* in_sizes, int n_in,
                              void* d_out, int out_size, void* d_ws, size_t ws_size,
                              hipStream_t stream) {
    const float* x     = (const float*)d_in[0];
    const int*   ei    = (const int*)d_in[1];
    const int*   batch = (const int*)d_in[2];
    const float* W0 = (const float*)d_in[3];
    const float* b0 = (const float*)d_in[4];
    const float* W1 = (const float*)d_in[5];
    const float* b1 = (const float*)d_in[6];
    const float* W2 = (const float*)d_in[7];
    const float* b2 = (const float*)d_in[8];
    const float* Wf = (const float*)d_in[9];
    const float* bf = (const float*)d_in[10];
    float* out = (float*)d_out;

    float* ws = (float*)d_ws;
    // float-offset layout
    float* sums    = ws;                      // 65536
    float* counts  = ws + 65536;              // 512
    int*   in_deg  = (int*)(ws + 66048);      // 50048
    int*   gcur    = (int*)(ws + 116096);     // 64
    float* dis     = ws + 116160;             // 50048
    int*   rowstart= (int*)(ws + 166208);     // 50048
    int*   cursor  = (int*)(ws + 216256);     // 50048
    int*   csr_src = (int*)(ws + 266304);     // 600064
    float* csr_w   = ws + 866368;             // 600064
    unsigned short* Wt = (unsigned short*)(ws + 1466432);   // 3*16384 ushort = 24576 f
    unsigned short* bx = (unsigned short*)(ws + 1491008);   // 6.4M ushort = 3.2M f
    unsigned short* hA = (unsigned short*)(ws + 4691008);   // 3.2M f
    unsigned short* hB = (unsigned short*)(ws + 7891008);   // 3.2M f

    const int* src = ei;
    const int* dst = ei + NE;

    // --- CSR build + norms + pool counts + conversions ---
    k_zero<<<(116160 + 255) / 256, 256, 0, stream>>>(ws, 116160);
    k_hist<<<2344, 256, 0, stream>>>(dst, in_deg);
    k_counts<<<196, 256, 0, stream>>>(batch, counts);
    k_alloc<<<196, 256, 0, stream>>>(in_deg, gcur, rowstart, cursor, dis);
    k_fill<<<2344, 256, 0, stream>>>(src, dst, dis, cursor, csr_src, csr_w);
    k_cvt_x<<<6250, 256, 0, stream>>>((const float4*)x, (uint2*)bx, NN * 32);
    k_cvt_w<<<192, 256, 0, stream>>>(W0, W1, W2, Wt);

    const int GEMM_GRID = (NN + 63) / 64;
    const int GATHER_GRID = (NN * 64 + 255) / 256;  // one wave per node

    // layer 0: bx -> hB (h@W0, bf16) -> hA (aggregate+bias+relu, bf16)
    k_gemm_mfma<<<GEMM_GRID, 256, 0, stream>>>(bx, Wt, hB, NN);
    k_gather<0><<<GATHER_GRID, 256, 0, stream>>>((const uint4*)hB, rowstart, cursor, csr_src, csr_w,
                                                 dis, b0, (uint4*)hA, batch, sums);
    // layer 1
    k_gemm_mfma<<<GEMM_GRID, 256, 0, stream>>>(hA, Wt + 16384, hB, NN);
    k_gather<0><<<GATHER_GRID, 256, 0, stream>>>((const uint4*)hB, rowstart, cursor, csr_src, csr_w,
                                                 dis, b1, (uint4*)hA, batch, sums);
    // layer 2: fuse bias+relu+mean-pool accumulate (f32 sums)
    k_gemm_mfma<<<GEMM_GRID, 256, 0, stream>>>(hA, Wt + 32768, hB, NN);
    k_gather<1><<<GATHER_GRID, 256, 0, stream>>>((const uint4*)hB, rowstart, cursor, csr_src, csr_w,
                                                 dis, b2, nullptr, batch, sums);

    k_head<<<512, 64, 0, stream>>>(sums, counts, Wf, bf, out);
}

// Round 5
// 363.513 us; speedup vs baseline: 1.3285x; 1.3285x over previous
//
#include <hip/hip_runtime.h>
#include <hip/hip_bf16.h>

#define NN 50000
#define NE 600000
#define NG 512

typedef __attribute__((ext_vector_type(8))) short bf16x8;
typedef __attribute__((ext_vector_type(4))) float f32x4;

__device__ __forceinline__ float bf_lo(unsigned u) {
    unsigned v = u << 16;
    return __builtin_bit_cast(float, v);
}
__device__ __forceinline__ float bf_hi(unsigned u) {
    unsigned v = u & 0xFFFF0000u;
    return __builtin_bit_cast(float, v);
}
__device__ __forceinline__ unsigned f2bf(float f) {  // RNE, returns in low 16 bits
    unsigned u = __builtin_bit_cast(unsigned, f);
    return (u + 0x7FFFu + ((u >> 16) & 1u)) >> 16;
}

__global__ __launch_bounds__(256) void k_zero(float* p, int n) {
    int i = blockIdx.x * 256 + threadIdx.x;
    if (i < n) p[i] = 0.0f;
}

__global__ __launch_bounds__(256) void k_hist(const int* __restrict__ dst, int* __restrict__ deg) {
    int e = blockIdx.x * 256 + threadIdx.x;
    if (e < NE) atomicAdd(&deg[dst[e]], 1);
}

__global__ __launch_bounds__(256) void k_counts(const int* __restrict__ batch, float* __restrict__ counts) {
    int i = blockIdx.x * 256 + threadIdx.x;
    if (i < NN) atomicAdd(&counts[batch[i]], 1.0f);
}

// allocate CSR row (padded to multiple of 4 slots); zero the pad slots
// (src=0, w=0 -> contributes nothing, row 0 is cache-hot).
__global__ __launch_bounds__(256) void k_alloc(const int* __restrict__ deg, int* __restrict__ gcur,
                                               int* __restrict__ rowstart, int* __restrict__ cursor,
                                               float* __restrict__ dis, uint2* __restrict__ cpk) {
    int i = blockIdx.x * 256 + threadIdx.x;
    if (i >= NN) return;
    int d = deg[i];
    int dr = (d + 3) & ~3;
    int st = atomicAdd(gcur, dr);
    rowstart[i] = st;
    cursor[i] = st;
    dis[i] = 1.0f / sqrtf((float)(d + 1));
    for (int p = st + d; p < st + dr; ++p) cpk[p] = make_uint2(0u, 0u);
}

// fill CSR slots: packed (src, weight). After this, cursor[i] == true row end.
__global__ __launch_bounds__(256) void k_fill(const int* __restrict__ src, const int* __restrict__ dst,
                                              const float* __restrict__ dis, int* __restrict__ cursor,
                                              uint2* __restrict__ cpk) {
    int e = blockIdx.x * 256 + threadIdx.x;
    if (e >= NE) return;
    int s = src[e], d = dst[e];
    int slot = atomicAdd(&cursor[d], 1);
    cpk[slot] = make_uint2((unsigned)s, __builtin_bit_cast(unsigned, dis[s] * dis[d]));
}

// x (f32) -> bf16 packed
__global__ __launch_bounds__(256) void k_cvt_x(const float4* __restrict__ in, uint2* __restrict__ out, int n4) {
    int i = blockIdx.x * 256 + threadIdx.x;
    if (i >= n4) return;
    float4 v = in[i];
    uint2 o;
    o.x = f2bf(v.x) | (f2bf(v.y) << 16);
    o.y = f2bf(v.z) | (f2bf(v.w) << 16);
    out[i] = o;
}

// W[k][c] f32 -> Wt[c][k] bf16, for 3 weight matrices
__global__ __launch_bounds__(256) void k_cvt_w(const float* __restrict__ W0, const float* __restrict__ W1,
                                               const float* __restrict__ W2, unsigned short* __restrict__ Wt) {
    int idx = blockIdx.x * 256 + threadIdx.x;
    if (idx >= 3 * 16384) return;
    int m = idx >> 14;
    int r = idx & 16383;
    int k = r >> 7, c = r & 127;
    const float* W = (m == 0) ? W0 : (m == 1) ? W1 : W2;
    Wt[m * 16384 + c * 128 + k] = (unsigned short)f2bf(W[k * 128 + c]);
}

// C[M,128](bf16) = A[M,128](bf16) @ W[128,128], W given transposed Wt[col][k] bf16.
// 256 thr = 4 waves; each wave: 16 rows x 128 cols via mfma_f32_16x16x32_bf16.
__global__ __launch_bounds__(256) void k_gemm_mfma(const unsigned short* __restrict__ A,
                                                   const unsigned short* __restrict__ Wt,
                                                   unsigned short* __restrict__ C, int M) {
    int wave = threadIdx.x >> 6;
    int lane = threadIdx.x & 63;
    int rowbase = blockIdx.x * 64 + wave * 16;
    int lr = lane & 15;   // A row within tile / B col within tile
    int kg = lane >> 4;   // k-group 0..3 (8 elems each)

    int arow = rowbase + lr;
    if (arow >= M) arow = M - 1;
    bf16x8 a[4];
#pragma unroll
    for (int kt = 0; kt < 4; ++kt)
        a[kt] = *(const bf16x8*)&A[arow * 128 + kt * 32 + kg * 8];

    f32x4 acc[8];
#pragma unroll
    for (int nt = 0; nt < 8; ++nt) acc[nt] = (f32x4){0.f, 0.f, 0.f, 0.f};

#pragma unroll
    for (int nt = 0; nt < 8; ++nt) {
        const unsigned short* wp = &Wt[(nt * 16 + lr) * 128 + kg * 8];
#pragma unroll
        for (int kt = 0; kt < 4; ++kt) {
            bf16x8 b = *(const bf16x8*)&wp[kt * 32];
            acc[nt] = __builtin_amdgcn_mfma_f32_16x16x32_bf16(a[kt], b, acc[nt], 0, 0, 0);
        }
    }

    int crow0 = rowbase + (lane >> 4) * 4;  // C/D: col = lane&15, row = (lane>>4)*4 + r
#pragma unroll
    for (int nt = 0; nt < 8; ++nt) {
#pragma unroll
        for (int r = 0; r < 4; ++r) {
            int gr = crow0 + r;
            if (gr < M) C[gr * 128 + nt * 16 + lr] = (unsigned short)f2bf(acc[nt][r]);
        }
    }
}

// Gather aggregation over bf16 features, 32 threads/node (uint2 = 4 bf16 each),
// 2 nodes per wave (the R3 shape). 4-deep manual unroll with 4 independent
// accumulator chains: CSR rows are padded to multiples of 4 with w=0 slots,
// so each iteration issues 2 aligned uint4 metadata loads + 4 independent
// h-row loads before any wait. f32 accumulate; fuses self-loop + bias + relu.
template <int POOL>
__global__ __launch_bounds__(256) void k_gather(const uint2* __restrict__ h,
                                                const int* __restrict__ rowstart,
                                                const int* __restrict__ rowend,
                                                const uint2* __restrict__ cpk,
                                                const float* __restrict__ dis,
                                                const float* __restrict__ bias,
                                                uint2* __restrict__ outbuf,
                                                const int* __restrict__ batch,
                                                float* __restrict__ sums) {
    int t = blockIdx.x * 256 + threadIdx.x;
    int node = t >> 5;
    if (node >= NN) return;
    int f = t & 31;  // cols f*4 .. f*4+3

    int s0 = rowstart[node];
    int e0 = rowend[node];  // true end; padded region extends to next mult of 4

    float A0 = 0.f, A1 = 0.f, A2 = 0.f, A3 = 0.f;
    float B0 = 0.f, B1 = 0.f, B2 = 0.f, B3 = 0.f;
    float C0 = 0.f, C1 = 0.f, C2 = 0.f, C3 = 0.f;
    float D0 = 0.f, D1 = 0.f, D2 = 0.f, D3 = 0.f;

    for (int s = s0; s < e0; s += 4) {
        uint4 q01 = *(const uint4*)&cpk[s];       // (src0,w0,src1,w1)
        uint4 q23 = *(const uint4*)&cpk[s + 2];   // (src2,w2,src3,w3)
        uint2 v0 = h[(int)q01.x * 32 + f];
        uint2 v1 = h[(int)q01.z * 32 + f];
        uint2 v2 = h[(int)q23.x * 32 + f];
        uint2 v3 = h[(int)q23.z * 32 + f];
        float w0 = __builtin_bit_cast(float, q01.y);
        float w1 = __builtin_bit_cast(float, q01.w);
        float w2 = __builtin_bit_cast(float, q23.y);
        float w3 = __builtin_bit_cast(float, q23.w);
        A0 = fmaf(bf_lo(v0.x), w0, A0);
        A1 = fmaf(bf_hi(v0.x), w0, A1);
        A2 = fmaf(bf_lo(v0.y), w0, A2);
        A3 = fmaf(bf_hi(v0.y), w0, A3);
        B0 = fmaf(bf_lo(v1.x), w1, B0);
        B1 = fmaf(bf_hi(v1.x), w1, B1);
        B2 = fmaf(bf_lo(v1.y), w1, B2);
        B3 = fmaf(bf_hi(v1.y), w1, B3);
        C0 = fmaf(bf_lo(v2.x), w2, C0);
        C1 = fmaf(bf_hi(v2.x), w2, C1);
        C2 = fmaf(bf_lo(v2.y), w2, C2);
        C3 = fmaf(bf_hi(v2.y), w2, C3);
        D0 = fmaf(bf_lo(v3.x), w3, D0);
        D1 = fmaf(bf_hi(v3.x), w3, D1);
        D2 = fmaf(bf_lo(v3.y), w3, D2);
        D3 = fmaf(bf_hi(v3.y), w3, D3);
    }

    // self-loop
    float d = dis[node];
    float w0 = d * d;
    uint2 hv = h[node * 32 + f];
    A0 = fmaf(bf_lo(hv.x), w0, A0);
    A1 = fmaf(bf_hi(hv.x), w0, A1);
    A2 = fmaf(bf_lo(hv.y), w0, A2);
    A3 = fmaf(bf_hi(hv.y), w0, A3);

    float a0 = (A0 + B0) + (C0 + D0);
    float a1 = (A1 + B1) + (C1 + D1);
    float a2 = (A2 + B2) + (C2 + D2);
    float a3 = (A3 + B3) + (C3 + D3);

    float4 b = ((const float4*)bias)[f];
    a0 = fmaxf(a0 + b.x, 0.f);
    a1 = fmaxf(a1 + b.y, 0.f);
    a2 = fmaxf(a2 + b.z, 0.f);
    a3 = fmaxf(a3 + b.w, 0.f);

    if (POOL == 0) {
        uint2 o;
        o.x = f2bf(a0) | (f2bf(a1) << 16);
        o.y = f2bf(a2) | (f2bf(a3) << 16);
        outbuf[node * 32 + f] = o;
    } else {
        int g = batch[node];
        float* o = sums + g * 128 + f * 4;
        atomicAdd(o + 0, a0);
        atomicAdd(o + 1, a1);
        atomicAdd(o + 2, a2);
        atomicAdd(o + 3, a3);
    }
}

// 512 blocks x 64 threads: pooled = sums/count; logits = pooled@Wf + bf; log_softmax
__global__ __launch_bounds__(64) void k_head(const float* __restrict__ sums,
                                             const float* __restrict__ counts,
                                             const float* __restrict__ Wf,
                                             const float* __restrict__ bf,
                                             float* __restrict__ out) {
    int g = blockIdx.x;
    int l = threadIdx.x;
    float inv = 1.0f / fmaxf(counts[g], 1.0f);
    float p0 = sums[g * 128 + l] * inv;
    float p1 = sums[g * 128 + 64 + l] * inv;
    float logit[10];
#pragma unroll
    for (int o = 0; o < 10; ++o) {
        float part = p0 * Wf[l * 10 + o] + p1 * Wf[(l + 64) * 10 + o];
#pragma unroll
        for (int s = 32; s > 0; s >>= 1) part += __shfl_xor(part, s);
        logit[o] = part + bf[o];
    }
    if (l == 0) {
        float m = logit[0];
#pragma unroll
        for (int o = 1; o < 10; ++o) m = fmaxf(m, logit[o]);
        float sum = 0.f;
#pragma unroll
        for (int o = 0; o < 10; ++o) sum += expf(logit[o] - m);
        float lse = m + logf(sum);
#pragma unroll
        for (int o = 0; o < 10; ++o) out[g * 10 + o] = logit[o] - lse;
    }
}

extern "C" void kernel_launch(void* const* d_in, const int* in_sizes, int n_in,
                              void* d_out, int out_size, void* d_ws, size_t ws_size,
                              hipStream_t stream) {
    const float* x     = (const float*)d_in[0];
    const int*   ei    = (const int*)d_in[1];
    const int*   batch = (const int*)d_in[2];
    const float* W0 = (const float*)d_in[3];
    const float* b0 = (const float*)d_in[4];
    const float* W1 = (const float*)d_in[5];
    const float* b1 = (const float*)d_in[6];
    const float* W2 = (const float*)d_in[7];
    const float* b2 = (const float*)d_in[8];
    const float* Wf = (const float*)d_in[9];
    const float* bf = (const float*)d_in[10];
    float* out = (float*)d_out;

    float* ws = (float*)d_ws;
    // float-offset layout
    float* sums    = ws;                      // 65536
    float* counts  = ws + 65536;              // 512
    int*   in_deg  = (int*)(ws + 66048);      // 50048
    int*   gcur    = (int*)(ws + 116096);     // 64
    float* dis     = ws + 116160;             // 50048
    int*   rowstart= (int*)(ws + 166208);     // 50048
    int*   cursor  = (int*)(ws + 216256);     // 50048
    uint2* cpk     = (uint2*)(ws + 266304);   // 800064 uint2 = 1600128 f (padded CSR)
    unsigned short* Wt = (unsigned short*)(ws + 1866432);   // 49152 ushort = 24576 f
    unsigned short* bx = (unsigned short*)(ws + 1891008);   // 3.2M f
    unsigned short* hA = (unsigned short*)(ws + 5091008);   // 3.2M f
    unsigned short* hB = (unsigned short*)(ws + 8291008);   // 3.2M f

    const int* src = ei;
    const int* dst = ei + NE;

    // --- CSR build + norms + pool counts + conversions ---
    k_zero<<<(116160 + 255) / 256, 256, 0, stream>>>(ws, 116160);
    k_hist<<<2344, 256, 0, stream>>>(dst, in_deg);
    k_counts<<<196, 256, 0, stream>>>(batch, counts);
    k_alloc<<<196, 256, 0, stream>>>(in_deg, gcur, rowstart, cursor, dis, cpk);
    k_fill<<<2344, 256, 0, stream>>>(src, dst, dis, cursor, cpk);
    k_cvt_x<<<6250, 256, 0, stream>>>((const float4*)x, (uint2*)bx, NN * 32);
    k_cvt_w<<<192, 256, 0, stream>>>(W0, W1, W2, Wt);

    const int GEMM_GRID = (NN + 63) / 64;

    // layer 0: bx -> hB (h@W0, bf16) -> hA (aggregate+bias+relu, bf16)
    k_gemm_mfma<<<GEMM_GRID, 256, 0, stream>>>(bx, Wt, hB, NN);
    k_gather<0><<<6250, 256, 0, stream>>>((const uint2*)hB, rowstart, cursor, cpk,
                                          dis, b0, (uint2*)hA, batch, sums);
    // layer 1
    k_gemm_mfma<<<GEMM_GRID, 256, 0, stream>>>(hA, Wt + 16384, hB, NN);
    k_gather<0><<<6250, 256, 0, stream>>>((const uint2*)hB, rowstart, cursor, cpk,
                                          dis, b1, (uint2*)hA, batch, sums);
    // layer 2: fuse bias+relu+mean-pool accumulate (f32 sums)
    k_gemm_mfma<<<GEMM_GRID, 256, 0, stream>>>(hA, Wt + 32768, hB, NN);
    k_gather<1><<<6250, 256, 0, stream>>>((const uint2*)hB, rowstart, cursor, cpk,
                                          dis, b2, nullptr, batch, sums);

    k_head<<<512, 64, 0, stream>>>(sums, counts, Wf, bf, out);
}